// Round 6
// baseline (299.232 us; speedup 1.0000x reference)
//
#include <hip/hip_runtime.h>

// ---------------------------------------------------------------------------
// Round 5: BK=64 GEMMs (half the barriers, XOR-swizzled DMA staging),
// unpaired flash (1024 blocks, 4/CU co-residency), fused prep kernel.
// B=4, S=2048, NH=16, DH=64, E=1024. fp32 I/O, bf16 compute, fp32 accum.
// ---------------------------------------------------------------------------

typedef __attribute__((ext_vector_type(8))) short short8;
typedef __attribute__((ext_vector_type(4))) float floatx4;

#define SCL 0.1803368801111244f   // (1/8) * log2(e), folded into Q projection

__device__ __forceinline__ unsigned short f2bf(float f) {
  unsigned int x = __float_as_uint(f);
  x += 0x7fffu + ((x >> 16) & 1u);   // RNE
  return (unsigned short)(x >> 16);
}

__device__ __forceinline__ void gload_lds16(const unsigned short* g, unsigned short* lds) {
  __builtin_amdgcn_global_load_lds(
      (const __attribute__((address_space(1))) void*)g,
      (__attribute__((address_space(3))) void*)lds, 16, 0, 0);
}

// ---------------- fused prep: cvt_x + W_QKV transpose + W_O transpose ------
// grid 9216: [0,8192) cvt_x ; [8192,8960) wqkv3 ; [8960,9216) wo
__global__ __launch_bounds__(256) void prep_kernel(
    const float* __restrict__ X,  unsigned short* __restrict__ Xb,
    const float* __restrict__ Wq, const float* __restrict__ Wk,
    const float* __restrict__ Wv, unsigned short* __restrict__ Bt,
    const float* __restrict__ Wo, unsigned short* __restrict__ Wt)
{
  __shared__ unsigned short T[64 * 72];
  const int bid = blockIdx.x, t = threadIdx.x;
  if (bid < 8192) {                                  // ---- x fp32 -> bf16
    int idx = ((bid << 8) + t) << 2;
    float4 f = *(const float4*)(X + idx);
    unsigned short u[4] = { f2bf(f.x), f2bf(f.y), f2bf(f.z), f2bf(f.w) };
    *(uint2*)(Xb + idx) = *(uint2*)u;
  } else if (bid < 8960) {                           // ---- W_{Q,K,V} transpose
    int b2 = bid - 8192;
    int e0 = (b2 & 15) << 6, nn = (b2 >> 4) & 15, proj = b2 >> 8;
    const float* W = (proj == 0) ? Wq : (proj == 1) ? Wk : Wv;
    const float* src = W + ((size_t)nn << 16) + ((size_t)e0 << 6);
#pragma unroll
    for (int rnd = 0; rnd < 4; ++rnd) {
      int off = (rnd << 10) + (t << 2);
      float4 f = *(const float4*)(src + off);
      int r = off >> 6, h = off & 63;
      T[r * 72 + h]     = f2bf(f.x);
      T[r * 72 + h + 1] = f2bf(f.y);
      T[r * 72 + h + 2] = f2bf(f.z);
      T[r * 72 + h + 3] = f2bf(f.w);
    }
    __syncthreads();
    const int h = t >> 2, ck = t & 3;
    size_t orow = ((size_t)((proj << 10) + (nn << 6) + h) << 10) + e0 + (ck << 4);
#pragma unroll
    for (int g = 0; g < 2; ++g) {
      unsigned short v[8];
#pragma unroll
      for (int j = 0; j < 8; ++j) v[j] = T[((ck << 4) + (g << 3) + j) * 72 + h];
      *(int4*)(Bt + orow + (g << 3)) = *(int4*)v;
    }
  } else {                                           // ---- W_O transpose
    int b2 = bid - 8960;
    int e0 = (b2 & 15) << 6, k0 = (b2 >> 4) << 6;
#pragma unroll
    for (int rnd = 0; rnd < 4; ++rnd) {
      int r = (rnd << 4) + (t >> 4);
      int c = (t & 15) << 2;
      float4 f = *(const float4*)(Wo + ((size_t)(k0 + r) << 10) + e0 + c);
      T[r * 72 + c]     = f2bf(f.x);
      T[r * 72 + c + 1] = f2bf(f.y);
      T[r * 72 + c + 2] = f2bf(f.z);
      T[r * 72 + c + 3] = f2bf(f.w);
    }
    __syncthreads();
    const int i = t >> 2, ck = t & 3;
    size_t orow = ((size_t)(e0 + i) << 10) + k0 + (ck << 4);
#pragma unroll
    for (int g = 0; g < 2; ++g) {
      unsigned short v[8];
#pragma unroll
      for (int j = 0; j < 8; ++j) v[j] = T[((ck << 4) + (g << 3) + j) * 72 + i];
      *(int4*)(Wt + orow + (g << 3)) = *(int4*)v;
    }
  }
}

// ---------------- 128x128 MFMA GEMM, BK=64 ---------------------------------
// LDS [128][64] with 16B blocks XOR-swizzled (blk ^= row&7) on the global
// side of the DMA (lane-linear LDS dest); readers un-swizzle with row&7.
// MODE 0: A=Xb, Bt=[3072][1024] -> Q(pre-scaled),K [B,N,S,D], Vt [B,N,D,S]
// MODE 1: A=Zb, Bt=Wo_t -> out fp32 [8192][1024] (+b_O)
template <int MODE>
__global__ __launch_bounds__(256) void gemm128_kernel(
    const unsigned short* __restrict__ A,
    const unsigned short* __restrict__ Bt,
    const float* __restrict__ b0, const float* __restrict__ b1,
    const float* __restrict__ b2,
    unsigned short* __restrict__ Oq, unsigned short* __restrict__ Ok,
    unsigned short* __restrict__ Ov, float* __restrict__ Of)
{
  const int K = 1024;
  __shared__ __align__(16) unsigned short As[8192];   // [128][64] swizzled
  __shared__ __align__(16) unsigned short Bs[8192];
  const int tid = threadIdx.x;
  const int l   = tid & 63, w = tid >> 6;
  const int l15 = l & 15,  lg = l >> 4;
  const int mo  = (w >> 1) << 6, no = (w & 1) << 6;
  const int m0  = blockIdx.y << 7, n0 = blockIdx.x << 7;
  const int srow = l >> 3;                   // 0..7 within 8-row DMA segment
  const int gblk = ((l & 7) ^ srow) << 3;    // global 16B-block (elems)
  const int rsw  = l15 & 7;                  // read-side row swizzle

  floatx4 acc[4][4];
#pragma unroll
  for (int i = 0; i < 4; ++i)
#pragma unroll
    for (int j = 0; j < 4; ++j) acc[i][j] = (floatx4){0.f, 0.f, 0.f, 0.f};

  for (int k0 = 0; k0 < K; k0 += 64) {
    __syncthreads();
#pragma unroll
    for (int s = 0; s < 4; ++s) {
      const int br = (s << 5) + (w << 3);    // wave-uniform base row
      gload_lds16(A  + (size_t)(m0 + br + srow) * K + k0 + gblk, &As[br << 6]);
      gload_lds16(Bt + (size_t)(n0 + br + srow) * K + k0 + gblk, &Bs[br << 6]);
    }
    __syncthreads();
#pragma unroll
    for (int kh = 0; kh < 2; ++kh) {
      const int bo = (((kh << 2) + lg) ^ rsw) << 3;
      short8 af[4], bf[4];
#pragma unroll
      for (int mc = 0; mc < 4; ++mc)
        af[mc] = *(const short8*)&As[((mo + (mc << 4) + l15) << 6) + bo];
#pragma unroll
      for (int nc = 0; nc < 4; ++nc)
        bf[nc] = *(const short8*)&Bs[((no + (nc << 4) + l15) << 6) + bo];
#pragma unroll
      for (int mc = 0; mc < 4; ++mc)
#pragma unroll
        for (int nc = 0; nc < 4; ++nc)
          acc[mc][nc] = __builtin_amdgcn_mfma_f32_16x16x32_bf16(af[mc], bf[nc], acc[mc][nc], 0, 0, 0);
    }
  }

  // C/D: col = l15, row = lg*4 + r
#pragma unroll
  for (int nc = 0; nc < 4; ++nc) {
    int c = n0 + no + (nc << 4) + l15;
    if (MODE == 1) {
      float bv = b0[c];
#pragma unroll
      for (int mc = 0; mc < 4; ++mc)
#pragma unroll
        for (int r = 0; r < 4; ++r) {
          int m = m0 + mo + (mc << 4) + (lg << 2) + r;
          Of[((size_t)m << 10) + c] = acc[mc][nc][r] + bv;
        }
    } else {
      int proj = c >> 10, cc = c & 1023;         // wave-uniform
      int hn = cc >> 6, h = cc & 63;
      const float* bp = (proj == 0) ? b0 : (proj == 1) ? b1 : b2;
      float bv = bp[cc];
      float sc = (proj == 0) ? SCL : 1.0f;       // softmax scale folded into Q
      if (proj < 2) {
        unsigned short* O = (proj == 0) ? Oq : Ok;
#pragma unroll
        for (int mc = 0; mc < 4; ++mc)
#pragma unroll
          for (int r = 0; r < 4; ++r) {
            int m = m0 + mo + (mc << 4) + (lg << 2) + r;
            int bb = m >> 11, ss = m & 2047;
            O[((((size_t)(bb << 4) + hn) << 11) + ss) * 64 + h] = f2bf((acc[mc][nc][r] + bv) * sc);
          }
      } else {                                   // V transposed: Vt[b][n][d][s]
#pragma unroll
        for (int mc = 0; mc < 4; ++mc) {
          int m = m0 + mo + (mc << 4) + (lg << 2);
          int bb = m >> 11, ss = m & 2047;
          unsigned short p0 = f2bf(acc[mc][nc][0] + bv);
          unsigned short p1 = f2bf(acc[mc][nc][1] + bv);
          unsigned short p2 = f2bf(acc[mc][nc][2] + bv);
          unsigned short p3 = f2bf(acc[mc][nc][3] + bv);
          uint2 pk;
          pk.x = (unsigned int)p0 | ((unsigned int)p1 << 16);
          pk.y = (unsigned int)p2 | ((unsigned int)p3 << 16);
          *(uint2*)&Ov[((((size_t)(bb << 4) + hn) << 6) + h) * 2048 + ss] = pk;
        }
      }
    }
  }
}

// ---------------- MFMA flash attention v4 ----------------------------------
// 1024 blocks, 1 q-tile (128 rows) each: x = (h8<<7) | (qtidx<<3) | xcd,
// qt = 15 - qtidx (heavy tiles dispatch first), head = xcd*8 + h8 (all 16
// q-tiles of a head on one XCD; 8 heads x 512 KB K/V = 4 MB = L2).
// 34 KB LDS -> 4 blocks/CU co-residency hides staging drains.
__global__ __launch_bounds__(256) void flash4_kernel(
    const unsigned short* __restrict__ Q,   // [B,N,S,D], pre-scaled by SCL
    const unsigned short* __restrict__ K,   // [B,N,S,D]
    const unsigned short* __restrict__ Vt,  // [B,N,D,S]
    unsigned short* __restrict__ Z)         // [B,S,N*D]
{
  __shared__ __align__(16) unsigned short Ks[4096];      // [key][d] swizzled
  __shared__ __align__(16) unsigned short Vs[4096];      // [d][key] swizzled
  __shared__ __align__(16) unsigned short Ps[4 * 2304];  // per-wave [q][key] stride 72

  const int tid = threadIdx.x;
  const int l   = tid & 63, w = tid >> 6;
  const int l15 = l & 15,  lg = l >> 4;
  const int x    = blockIdx.x;
  const int qt   = 15 - ((x >> 3) & 15);
  const int head = ((x & 7) << 3) + (x >> 7);
  const int n = head & 15, b = head >> 4;
  const size_t hoff = (size_t)head << 17;
  const unsigned short* Qh = Q + hoff;
  const unsigned short* Kh = K + hoff;
  const unsigned short* Vh = Vt + hoff;
  unsigned short* Psw = Ps + w * 2304;

  const int srow8 = l >> 3;
  const int sblk8 = ((l & 7) ^ srow8) << 3;
  const int swz   = l15 & 7;
  const int bo0   = (lg ^ swz) << 3;
  const int bo1   = ((4 + lg) ^ swz) << 3;

  short8 onef;
#pragma unroll
  for (int i = 0; i < 8; ++i) onef[i] = (short)0x3F80;   // bf16 1.0

  const int q0w = (qt << 7) + (w << 5);

  short8 qf[2][2];
#pragma unroll
  for (int qc = 0; qc < 2; ++qc)
#pragma unroll
    for (int dh = 0; dh < 2; ++dh)
      qf[qc][dh] = *(const short8*)(Qh + (size_t)(q0w + (qc << 4) + l15) * 64 + (dh << 5) + (lg << 3));

  floatx4 acc_o[2][4], acc_l[2];
#pragma unroll
  for (int qc = 0; qc < 2; ++qc) {
    acc_l[qc] = (floatx4){0.f, 0.f, 0.f, 0.f};
#pragma unroll
    for (int dc = 0; dc < 4; ++dc) acc_o[qc][dc] = (floatx4){0.f, 0.f, 0.f, 0.f};
  }

  const int nkt = (qt << 1) + 2;
  for (int kt = 0; kt < nkt; ++kt) {
    const int k0 = kt << 6;
    __syncthreads();
#pragma unroll
    for (int j = 0; j < 2; ++j) {
      const int s = (w << 1) + j;
      gload_lds16(Kh + (size_t)(k0 + (s << 3) + srow8) * 64 + sblk8, &Ks[s << 9]);
      gload_lds16(Vh + (size_t)((s << 3) + srow8) * 2048 + k0 + sblk8, &Vs[s << 9]);
    }
    __syncthreads();
    if (k0 > q0w + 31) continue;             // wave fully masked

    // ---- S^T[key][q] = K * Q^T ----
    floatx4 s0[4], s1[4];
#pragma unroll
    for (int mc = 0; mc < 4; ++mc) {
      s0[mc] = (floatx4){0.f, 0.f, 0.f, 0.f};
      s1[mc] = (floatx4){0.f, 0.f, 0.f, 0.f};
    }
#pragma unroll
    for (int dh = 0; dh < 2; ++dh) {
      const int bo = dh ? bo1 : bo0;
#pragma unroll
      for (int mc = 0; mc < 4; ++mc) {
        short8 ak = *(const short8*)&Ks[(((mc << 4) + l15) << 6) + bo];
        s0[mc] = __builtin_amdgcn_mfma_f32_16x16x32_bf16(ak, qf[0][dh], s0[mc], 0, 0, 0);
        s1[mc] = __builtin_amdgcn_mfma_f32_16x16x32_bf16(ak, qf[1][dh], s1[mc], 0, 0, 0);
      }
    }

    // ---- p = 2^s; mask only on diagonal tiles; truncation-pack ----
    const bool needmask = (k0 + 63 > q0w);
#pragma unroll
    for (int qc = 0; qc < 2; ++qc) {
      const int qg = q0w + (qc << 4) + l15;
#pragma unroll
      for (int mc = 0; mc < 4; ++mc) {
        float p[4];
#pragma unroll
        for (int r = 0; r < 4; ++r) {
          float e = exp2f(qc ? s1[mc][r] : s0[mc][r]);
          if (needmask) {
            int key = k0 + (mc << 4) + (lg << 2) + r;
            e = (key > qg) ? 0.f : e;
          }
          p[r] = e;
        }
        uint2 pk;
        pk.x = (__float_as_uint(p[1]) & 0xFFFF0000u) | (__float_as_uint(p[0]) >> 16);
        pk.y = (__float_as_uint(p[3]) & 0xFFFF0000u) | (__float_as_uint(p[2]) >> 16);
        *(uint2*)&Psw[((qc << 4) + l15) * 72 + (mc << 4) + (lg << 2)] = pk;
      }
    }

    // ---- PV: O += P*V ; l += P*ones ----
    short8 pa[2][2];
#pragma unroll
    for (int qc = 0; qc < 2; ++qc)
#pragma unroll
      for (int kc = 0; kc < 2; ++kc)
        pa[qc][kc] = *(const short8*)&Psw[((qc << 4) + l15) * 72 + (kc << 5) + (lg << 3)];
#pragma unroll
    for (int kc = 0; kc < 2; ++kc) {
      const int bo = kc ? bo1 : bo0;
#pragma unroll
      for (int dc = 0; dc < 4; ++dc) {
        short8 vb = *(const short8*)&Vs[(((dc << 4) + l15) << 6) + bo];
        acc_o[0][dc] = __builtin_amdgcn_mfma_f32_16x16x32_bf16(pa[0][kc], vb, acc_o[0][dc], 0, 0, 0);
        acc_o[1][dc] = __builtin_amdgcn_mfma_f32_16x16x32_bf16(pa[1][kc], vb, acc_o[1][dc], 0, 0, 0);
      }
      acc_l[0] = __builtin_amdgcn_mfma_f32_16x16x32_bf16(pa[0][kc], onef, acc_l[0], 0, 0, 0);
      acc_l[1] = __builtin_amdgcn_mfma_f32_16x16x32_bf16(pa[1][kc], onef, acc_l[1], 0, 0, 0);
    }
  }

  // ---- epilogue: Z = O / l ----
#pragma unroll
  for (int qc = 0; qc < 2; ++qc) {
    floatx4 inv;
#pragma unroll
    for (int r = 0; r < 4; ++r) inv[r] = 1.f / acc_l[qc][r];
#pragma unroll
    for (int dc = 0; dc < 4; ++dc)
#pragma unroll
      for (int r = 0; r < 4; ++r) {
        int qg = q0w + (qc << 4) + (lg << 2) + r;
        Z[(((size_t)b << 11) + qg) * 1024 + (n << 6) + (dc << 4) + l15] =
            f2bf(acc_o[qc][dc][r] * inv[r]);
      }
  }
}

// ---------------------------------------------------------------------------
extern "C" void kernel_launch(void* const* d_in, const int* in_sizes, int n_in,
                              void* d_out, int out_size, void* d_ws, size_t ws_size,
                              hipStream_t stream) {
  const float* x   = (const float*)d_in[0];
  const float* W_Q = (const float*)d_in[1];
  const float* b_Q = (const float*)d_in[2];
  const float* W_K = (const float*)d_in[3];
  const float* b_K = (const float*)d_in[4];
  const float* W_V = (const float*)d_in[5];
  const float* b_V = (const float*)d_in[6];
  const float* W_O = (const float*)d_in[7];
  const float* b_O = (const float*)d_in[8];
  float* out = (float*)d_out;

  unsigned short* ws    = (unsigned short*)d_ws;
  unsigned short* BtQKV = ws;                        // [3072][1024]
  unsigned short* Wo_t  = BtQKV + (3u << 20);        // [1024][1024]
  unsigned short* Xb    = Wo_t + (1u << 20);         // [8192][1024]
  unsigned short* Qb    = Xb + (8u << 20);           // [B,N,S,D]
  unsigned short* Kb    = Qb + (8u << 20);
  unsigned short* Vtb   = Kb + (8u << 20);           // [B,N,D,S]
  unsigned short* Zb    = Vtb + (8u << 20);          // [B,S,N*D]

  prep_kernel<<<9216, 256, 0, stream>>>(x, Xb, W_Q, W_K, W_V, BtQKV, W_O, Wo_t);

  gemm128_kernel<0><<<dim3(24, 64), 256, 0, stream>>>(
      Xb, BtQKV, b_Q, b_K, b_V, Qb, Kb, Vtb, nullptr);

  flash4_kernel<<<1024, 256, 0, stream>>>(Qb, Kb, Vtb, Zb);

  gemm128_kernel<1><<<dim3(8, 64), 256, 0, stream>>>(
      Zb, Wo_t, b_O, nullptr, nullptr, nullptr, nullptr, nullptr, out);
}

// Round 7
// 282.266 us; speedup vs baseline: 1.0601x; 1.0601x over previous
//
#include <hip/hip_runtime.h>

// ---------------------------------------------------------------------------
// Round 6: flash rebuilt for uniform per-block work at high co-residency:
// 128-thread blocks, paired 64-row q-tiles (31-p, p) = 33 k-tiles/block,
// 1024 blocks, 25.4 KB LDS -> 6 blocks/CU. GEMMs (BK=64) + fused prep kept.
// B=4, S=2048, NH=16, DH=64, E=1024. fp32 I/O, bf16 compute, fp32 accum.
// ---------------------------------------------------------------------------

typedef __attribute__((ext_vector_type(8))) short short8;
typedef __attribute__((ext_vector_type(4))) float floatx4;

#define SCL 0.1803368801111244f   // (1/8) * log2(e), folded into Q projection

__device__ __forceinline__ unsigned short f2bf(float f) {
  unsigned int x = __float_as_uint(f);
  x += 0x7fffu + ((x >> 16) & 1u);   // RNE
  return (unsigned short)(x >> 16);
}

__device__ __forceinline__ void gload_lds16(const unsigned short* g, unsigned short* lds) {
  __builtin_amdgcn_global_load_lds(
      (const __attribute__((address_space(1))) void*)g,
      (__attribute__((address_space(3))) void*)lds, 16, 0, 0);
}

// ---------------- fused prep: cvt_x + W_QKV transpose + W_O transpose ------
__global__ __launch_bounds__(256) void prep_kernel(
    const float* __restrict__ X,  unsigned short* __restrict__ Xb,
    const float* __restrict__ Wq, const float* __restrict__ Wk,
    const float* __restrict__ Wv, unsigned short* __restrict__ Bt,
    const float* __restrict__ Wo, unsigned short* __restrict__ Wt)
{
  __shared__ unsigned short T[64 * 72];
  const int bid = blockIdx.x, t = threadIdx.x;
  if (bid < 8192) {                                  // ---- x fp32 -> bf16
    int idx = ((bid << 8) + t) << 2;
    float4 f = *(const float4*)(X + idx);
    unsigned short u[4] = { f2bf(f.x), f2bf(f.y), f2bf(f.z), f2bf(f.w) };
    *(uint2*)(Xb + idx) = *(uint2*)u;
  } else if (bid < 8960) {                           // ---- W_{Q,K,V} transpose
    int b2 = bid - 8192;
    int e0 = (b2 & 15) << 6, nn = (b2 >> 4) & 15, proj = b2 >> 8;
    const float* W = (proj == 0) ? Wq : (proj == 1) ? Wk : Wv;
    const float* src = W + ((size_t)nn << 16) + ((size_t)e0 << 6);
#pragma unroll
    for (int rnd = 0; rnd < 4; ++rnd) {
      int off = (rnd << 10) + (t << 2);
      float4 f = *(const float4*)(src + off);
      int r = off >> 6, h = off & 63;
      T[r * 72 + h]     = f2bf(f.x);
      T[r * 72 + h + 1] = f2bf(f.y);
      T[r * 72 + h + 2] = f2bf(f.z);
      T[r * 72 + h + 3] = f2bf(f.w);
    }
    __syncthreads();
    const int h = t >> 2, ck = t & 3;
    size_t orow = ((size_t)((proj << 10) + (nn << 6) + h) << 10) + e0 + (ck << 4);
#pragma unroll
    for (int g = 0; g < 2; ++g) {
      unsigned short v[8];
#pragma unroll
      for (int j = 0; j < 8; ++j) v[j] = T[((ck << 4) + (g << 3) + j) * 72 + h];
      *(int4*)(Bt + orow + (g << 3)) = *(int4*)v;
    }
  } else {                                           // ---- W_O transpose
    int b2 = bid - 8960;
    int e0 = (b2 & 15) << 6, k0 = (b2 >> 4) << 6;
#pragma unroll
    for (int rnd = 0; rnd < 4; ++rnd) {
      int r = (rnd << 4) + (t >> 4);
      int c = (t & 15) << 2;
      float4 f = *(const float4*)(Wo + ((size_t)(k0 + r) << 10) + e0 + c);
      T[r * 72 + c]     = f2bf(f.x);
      T[r * 72 + c + 1] = f2bf(f.y);
      T[r * 72 + c + 2] = f2bf(f.z);
      T[r * 72 + c + 3] = f2bf(f.w);
    }
    __syncthreads();
    const int i = t >> 2, ck = t & 3;
    size_t orow = ((size_t)(e0 + i) << 10) + k0 + (ck << 4);
#pragma unroll
    for (int g = 0; g < 2; ++g) {
      unsigned short v[8];
#pragma unroll
      for (int j = 0; j < 8; ++j) v[j] = T[((ck << 4) + (g << 3) + j) * 72 + i];
      *(int4*)(Wt + orow + (g << 3)) = *(int4*)v;
    }
  }
}

// ---------------- 128x128 MFMA GEMM, BK=64 (round-5, kept) -----------------
template <int MODE>
__global__ __launch_bounds__(256) void gemm128_kernel(
    const unsigned short* __restrict__ A,
    const unsigned short* __restrict__ Bt,
    const float* __restrict__ b0, const float* __restrict__ b1,
    const float* __restrict__ b2,
    unsigned short* __restrict__ Oq, unsigned short* __restrict__ Ok,
    unsigned short* __restrict__ Ov, float* __restrict__ Of)
{
  const int K = 1024;
  __shared__ __align__(16) unsigned short As[8192];   // [128][64] swizzled
  __shared__ __align__(16) unsigned short Bs[8192];
  const int tid = threadIdx.x;
  const int l   = tid & 63, w = tid >> 6;
  const int l15 = l & 15,  lg = l >> 4;
  const int mo  = (w >> 1) << 6, no = (w & 1) << 6;
  const int m0  = blockIdx.y << 7, n0 = blockIdx.x << 7;
  const int srow = l >> 3;
  const int gblk = ((l & 7) ^ srow) << 3;
  const int rsw  = l15 & 7;

  floatx4 acc[4][4];
#pragma unroll
  for (int i = 0; i < 4; ++i)
#pragma unroll
    for (int j = 0; j < 4; ++j) acc[i][j] = (floatx4){0.f, 0.f, 0.f, 0.f};

  for (int k0 = 0; k0 < K; k0 += 64) {
    __syncthreads();
#pragma unroll
    for (int s = 0; s < 4; ++s) {
      const int br = (s << 5) + (w << 3);
      gload_lds16(A  + (size_t)(m0 + br + srow) * K + k0 + gblk, &As[br << 6]);
      gload_lds16(Bt + (size_t)(n0 + br + srow) * K + k0 + gblk, &Bs[br << 6]);
    }
    __syncthreads();
#pragma unroll
    for (int kh = 0; kh < 2; ++kh) {
      const int bo = (((kh << 2) + lg) ^ rsw) << 3;
      short8 af[4], bf[4];
#pragma unroll
      for (int mc = 0; mc < 4; ++mc)
        af[mc] = *(const short8*)&As[((mo + (mc << 4) + l15) << 6) + bo];
#pragma unroll
      for (int nc = 0; nc < 4; ++nc)
        bf[nc] = *(const short8*)&Bs[((no + (nc << 4) + l15) << 6) + bo];
#pragma unroll
      for (int mc = 0; mc < 4; ++mc)
#pragma unroll
        for (int nc = 0; nc < 4; ++nc)
          acc[mc][nc] = __builtin_amdgcn_mfma_f32_16x16x32_bf16(af[mc], bf[nc], acc[mc][nc], 0, 0, 0);
    }
  }

#pragma unroll
  for (int nc = 0; nc < 4; ++nc) {
    int c = n0 + no + (nc << 4) + l15;
    if (MODE == 1) {
      float bv = b0[c];
#pragma unroll
      for (int mc = 0; mc < 4; ++mc)
#pragma unroll
        for (int r = 0; r < 4; ++r) {
          int m = m0 + mo + (mc << 4) + (lg << 2) + r;
          Of[((size_t)m << 10) + c] = acc[mc][nc][r] + bv;
        }
    } else {
      int proj = c >> 10, cc = c & 1023;         // wave-uniform
      int hn = cc >> 6, h = cc & 63;
      const float* bp = (proj == 0) ? b0 : (proj == 1) ? b1 : b2;
      float bv = bp[cc];
      float sc = (proj == 0) ? SCL : 1.0f;
      if (proj < 2) {
        unsigned short* O = (proj == 0) ? Oq : Ok;
#pragma unroll
        for (int mc = 0; mc < 4; ++mc)
#pragma unroll
          for (int r = 0; r < 4; ++r) {
            int m = m0 + mo + (mc << 4) + (lg << 2) + r;
            int bb = m >> 11, ss = m & 2047;
            O[((((size_t)(bb << 4) + hn) << 11) + ss) * 64 + h] = f2bf((acc[mc][nc][r] + bv) * sc);
          }
      } else {                                   // V transposed: Vt[b][n][d][s]
#pragma unroll
        for (int mc = 0; mc < 4; ++mc) {
          int m = m0 + mo + (mc << 4) + (lg << 2);
          int bb = m >> 11, ss = m & 2047;
          unsigned short p0 = f2bf(acc[mc][nc][0] + bv);
          unsigned short p1 = f2bf(acc[mc][nc][1] + bv);
          unsigned short p2 = f2bf(acc[mc][nc][2] + bv);
          unsigned short p3 = f2bf(acc[mc][nc][3] + bv);
          uint2 pk;
          pk.x = (unsigned int)p0 | ((unsigned int)p1 << 16);
          pk.y = (unsigned int)p2 | ((unsigned int)p3 << 16);
          *(uint2*)&Ov[((((size_t)(bb << 4) + hn) << 6) + h) * 2048 + ss] = pk;
        }
      }
    }
  }
}

// ---------------- MFMA flash attention v5 ----------------------------------
// 1024 blocks x 128 threads (2 waves x 32 q-rows = 64-row q-tile).
// Each block: paired q-tiles (31-p, p) -> 33 k-tiles, UNIFORM across all
// blocks (immune to block->CU assignment). head = (x&7)*8 + (x>>7): all 32
// q-tiles of a head on one XCD (8 heads x 512 KB K/V = 4 MB = L2/XCD).
// LDS 25.4 KB -> 6 blocks/CU co-resident hides staging drains.
__global__ __launch_bounds__(128) void flash5_kernel(
    const unsigned short* __restrict__ Q,   // [B,N,S,D], pre-scaled by SCL
    const unsigned short* __restrict__ K,   // [B,N,S,D]
    const unsigned short* __restrict__ Vt,  // [B,N,D,S]
    unsigned short* __restrict__ Z)         // [B,S,N*D]
{
  __shared__ __align__(16) unsigned short Ks[4096];      // [key][d] swizzled
  __shared__ __align__(16) unsigned short Vs[4096];      // [d][key] swizzled
  __shared__ __align__(16) unsigned short Ps[2 * 2304];  // per-wave [q][key] s72

  const int tid = threadIdx.x;
  const int l   = tid & 63, w = tid >> 6;               // w in {0,1}
  const int l15 = l & 15,  lg = l >> 4;
  const int x    = blockIdx.x;
  const int pidx = (x >> 3) & 15;                       // pair index 0..15
  const int head = ((x & 7) << 3) + (x >> 7);
  const int n = head & 15, b = head >> 4;
  const size_t hoff = (size_t)head << 17;
  const unsigned short* Qh = Q + hoff;
  const unsigned short* Kh = K + hoff;
  const unsigned short* Vh = Vt + hoff;
  unsigned short* Psw = Ps + w * 2304;

  const int srow8 = l >> 3;
  const int sblk8 = ((l & 7) ^ srow8) << 3;
  const int swz   = l15 & 7;
  const int bo0   = (lg ^ swz) << 3;
  const int bo1   = ((4 + lg) ^ swz) << 3;

  short8 onef;
#pragma unroll
  for (int i = 0; i < 8; ++i) onef[i] = (short)0x3F80;   // bf16 1.0

  for (int half = 0; half < 2; ++half) {
    const int qt  = half ? pidx : (31 - pidx);           // heavy tile first
    const int q0w = (qt << 6) + (w << 5);

    short8 qf[2][2];
#pragma unroll
    for (int qc = 0; qc < 2; ++qc)
#pragma unroll
      for (int dh = 0; dh < 2; ++dh)
        qf[qc][dh] = *(const short8*)(Qh + (size_t)(q0w + (qc << 4) + l15) * 64 + (dh << 5) + (lg << 3));

    floatx4 acc_o[2][4], acc_l[2];
#pragma unroll
    for (int qc = 0; qc < 2; ++qc) {
      acc_l[qc] = (floatx4){0.f, 0.f, 0.f, 0.f};
#pragma unroll
      for (int dc = 0; dc < 4; ++dc) acc_o[qc][dc] = (floatx4){0.f, 0.f, 0.f, 0.f};
    }

    const int nkt = qt + 1;                              // 64-row tile, 64-key tiles
    for (int kt = 0; kt < nkt; ++kt) {
      const int k0 = kt << 6;
      __syncthreads();
#pragma unroll
      for (int j = 0; j < 4; ++j) {
        const int s = (w << 2) + j;                      // segment 0..7
        gload_lds16(Kh + (size_t)(k0 + (s << 3) + srow8) * 64 + sblk8, &Ks[s << 9]);
        gload_lds16(Vh + (size_t)((s << 3) + srow8) * 2048 + k0 + sblk8, &Vs[s << 9]);
      }
      __syncthreads();

      // ---- S^T[key][q] = K * Q^T ----
      floatx4 s0[4], s1[4];
#pragma unroll
      for (int mc = 0; mc < 4; ++mc) {
        s0[mc] = (floatx4){0.f, 0.f, 0.f, 0.f};
        s1[mc] = (floatx4){0.f, 0.f, 0.f, 0.f};
      }
#pragma unroll
      for (int dh = 0; dh < 2; ++dh) {
        const int bo = dh ? bo1 : bo0;
#pragma unroll
        for (int mc = 0; mc < 4; ++mc) {
          short8 ak = *(const short8*)&Ks[(((mc << 4) + l15) << 6) + bo];
          s0[mc] = __builtin_amdgcn_mfma_f32_16x16x32_bf16(ak, qf[0][dh], s0[mc], 0, 0, 0);
          s1[mc] = __builtin_amdgcn_mfma_f32_16x16x32_bf16(ak, qf[1][dh], s1[mc], 0, 0, 0);
        }
      }

      // ---- p = 2^s; mask only on diagonal tiles; truncation-pack ----
      const bool needmask = (k0 + 63 > q0w);
#pragma unroll
      for (int qc = 0; qc < 2; ++qc) {
        const int qg = q0w + (qc << 4) + l15;
#pragma unroll
        for (int mc = 0; mc < 4; ++mc) {
          float p[4];
#pragma unroll
          for (int r = 0; r < 4; ++r) {
            float e = exp2f(qc ? s1[mc][r] : s0[mc][r]);
            if (needmask) {
              int key = k0 + (mc << 4) + (lg << 2) + r;
              e = (key > qg) ? 0.f : e;
            }
            p[r] = e;
          }
          uint2 pk;
          pk.x = (__float_as_uint(p[1]) & 0xFFFF0000u) | (__float_as_uint(p[0]) >> 16);
          pk.y = (__float_as_uint(p[3]) & 0xFFFF0000u) | (__float_as_uint(p[2]) >> 16);
          *(uint2*)&Psw[((qc << 4) + l15) * 72 + (mc << 4) + (lg << 2)] = pk;
        }
      }

      // ---- PV: O += P*V ; l += P*ones ----
      short8 pa[2][2];
#pragma unroll
      for (int qc = 0; qc < 2; ++qc)
#pragma unroll
        for (int kc = 0; kc < 2; ++kc)
          pa[qc][kc] = *(const short8*)&Psw[((qc << 4) + l15) * 72 + (kc << 5) + (lg << 3)];
#pragma unroll
      for (int kc = 0; kc < 2; ++kc) {
        const int bo = kc ? bo1 : bo0;
#pragma unroll
        for (int dc = 0; dc < 4; ++dc) {
          short8 vb = *(const short8*)&Vs[(((dc << 4) + l15) << 6) + bo];
          acc_o[0][dc] = __builtin_amdgcn_mfma_f32_16x16x32_bf16(pa[0][kc], vb, acc_o[0][dc], 0, 0, 0);
          acc_o[1][dc] = __builtin_amdgcn_mfma_f32_16x16x32_bf16(pa[1][kc], vb, acc_o[1][dc], 0, 0, 0);
        }
        acc_l[0] = __builtin_amdgcn_mfma_f32_16x16x32_bf16(pa[0][kc], onef, acc_l[0], 0, 0, 0);
        acc_l[1] = __builtin_amdgcn_mfma_f32_16x16x32_bf16(pa[1][kc], onef, acc_l[1], 0, 0, 0);
      }
    }

    // ---- epilogue: Z = O / l ----
#pragma unroll
    for (int qc = 0; qc < 2; ++qc) {
      floatx4 inv;
#pragma unroll
      for (int r = 0; r < 4; ++r) inv[r] = 1.f / acc_l[qc][r];
#pragma unroll
      for (int dc = 0; dc < 4; ++dc)
#pragma unroll
        for (int r = 0; r < 4; ++r) {
          int qg = q0w + (qc << 4) + (lg << 2) + r;
          Z[(((size_t)b << 11) + qg) * 1024 + (n << 6) + (dc << 4) + l15] =
              f2bf(acc_o[qc][dc][r] * inv[r]);
        }
    }
  }
}

// ---------------------------------------------------------------------------
extern "C" void kernel_launch(void* const* d_in, const int* in_sizes, int n_in,
                              void* d_out, int out_size, void* d_ws, size_t ws_size,
                              hipStream_t stream) {
  const float* x   = (const float*)d_in[0];
  const float* W_Q = (const float*)d_in[1];
  const float* b_Q = (const float*)d_in[2];
  const float* W_K = (const float*)d_in[3];
  const float* b_K = (const float*)d_in[4];
  const float* W_V = (const float*)d_in[5];
  const float* b_V = (const float*)d_in[6];
  const float* W_O = (const float*)d_in[7];
  const float* b_O = (const float*)d_in[8];
  float* out = (float*)d_out;

  unsigned short* ws    = (unsigned short*)d_ws;
  unsigned short* BtQKV = ws;                        // [3072][1024]
  unsigned short* Wo_t  = BtQKV + (3u << 20);        // [1024][1024]
  unsigned short* Xb    = Wo_t + (1u << 20);         // [8192][1024]
  unsigned short* Qb    = Xb + (8u << 20);           // [B,N,S,D]
  unsigned short* Kb    = Qb + (8u << 20);
  unsigned short* Vtb   = Kb + (8u << 20);           // [B,N,D,S]
  unsigned short* Zb    = Vtb + (8u << 20);          // [B,S,N*D]

  prep_kernel<<<9216, 256, 0, stream>>>(x, Xb, W_Q, W_K, W_V, BtQKV, W_O, Wo_t);

  gemm128_kernel<0><<<dim3(24, 64), 256, 0, stream>>>(
      Xb, BtQKV, b_Q, b_K, b_V, Qb, Kb, Vtb, nullptr);

  flash5_kernel<<<1024, 128, 0, stream>>>(Qb, Kb, Vtb, Zb);

  gemm128_kernel<1><<<dim3(8, 64), 256, 0, stream>>>(
      Zb, Wo_t, b_O, nullptr, nullptr, nullptr, nullptr, nullptr, out);
}